// Round 5
// baseline (174.597 us; speedup 1.0000x reference)
//
#include <hip/hip_runtime.h>

// Problem constants (fixed by setup_inputs: shape (1,32,96,240), max_disp=192)
#define CC   32          // channels per input image
#define HH   96
#define WW   240
#define DD   64          // disparities = 192/3
#define W4   60          // WW/4 float4 per row
#define HQ   4           // rows per block
#define NHQ  (HH / HQ)   // 24 h-strips
#define SLICE_F4 (HH * W4)   // 5760 float4 per (s,c,d) slice (92160 B)

typedef float vf4 __attribute__((ext_vector_type(4)));

// out[s, 0, cout, d, h, w]:
//   cout <  CC : (w>=d) ? L_s[cout,h,w]        : 0
//   cout >= CC : (w>=d) ? R_s[cout-CC,h,w-d]   : 0
//
// One block = (s, half, c, 4-row strip), looping over ALL 64 d values.
// The input window (4 rows x 960 B) is read once: left half hoists it into
// registers (no loads in the d-loop at all); right half re-reads shifted
// positions from L1-hot lines. Global read traffic = 11.8 MB total -> the
// kernel is a near-pure write stream (like fillBuffer, which runs 6.7 TB/s).
__global__ __launch_bounds__(256) void cost_volume_kernel(
        const float* __restrict__ l0, const float* __restrict__ r0,
        const float* __restrict__ l1, const float* __restrict__ r1,
        float* __restrict__ out) {
    // blockIdx.x = ((s*2 + half)*CC + c)*NHQ + hq
    unsigned b = blockIdx.x;
    const unsigned hq   = b % NHQ;  b /= NHQ;   // one scalar magic-div per block
    const unsigned c    = b & (CC - 1u);  b >>= 5;
    const unsigned half = b & 1u;
    const unsigned s    = b >> 1;

    const unsigned tid = threadIdx.x;
    if (tid >= 240) return;                    // 240 workers: (r, col)
    const unsigned r   = tid / 60u;            // once
    const unsigned col = tid - r * 60u;
    const unsigned w0  = col * 4u;

    const float* img = half ? (s ? r1 : r0) : (s ? l1 : l0);
    const float* row = img + (c * HH + hq * HQ + r) * WW;

    const unsigned cout = half * CC + c;
    size_t of = (size_t)(s * 2u * CC + cout) * DD * SLICE_F4
              + (size_t)(hq * HQ + r) * W4 + col;   // f4 index at d=0
    vf4* o4 = reinterpret_cast<vf4*>(out);

    if (!half) {
        // Left: value independent of d except for the mask. Load ONCE.
        const vf4 x = *reinterpret_cast<const vf4*>(row + w0);
        const int iw0 = (int)w0;
#pragma unroll 4
        for (int d = 0; d < DD; ++d) {
            const int a = iw0 - d;             // mask: a + j >= 0
            vf4 v;
            v.x = (a + 0 >= 0) ? x.x : 0.0f;
            v.y = (a + 1 >= 0) ? x.y : 0.0f;
            v.z = (a + 2 >= 0) ? x.z : 0.0f;
            v.w = (a + 3 >= 0) ? x.w : 0.0f;
            o4[of] = v;
            of += SLICE_F4;
        }
    } else {
        // Right: shifted read, L1-hot after first pass over the window.
        const int iw0 = (int)w0;
#pragma unroll 4
        for (int d = 0; d < DD; ++d) {
            const int a = iw0 - d;             // source dword; clamp keeps in-bounds
            const int a0 = (a + 0 > 0) ? a + 0 : 0;
            const int a1 = (a + 1 > 0) ? a + 1 : 0;
            const int a2 = (a + 2 > 0) ? a + 2 : 0;
            const int a3 = (a + 3 > 0) ? a + 3 : 0;
            vf4 v;
            v.x = (a + 0 >= 0) ? row[a0] : 0.0f;
            v.y = (a + 1 >= 0) ? row[a1] : 0.0f;
            v.z = (a + 2 >= 0) ? row[a2] : 0.0f;
            v.w = (a + 3 >= 0) ? row[a3] : 0.0f;
            o4[of] = v;
            of += SLICE_F4;
        }
    }
}

extern "C" void kernel_launch(void* const* d_in, const int* in_sizes, int n_in,
                              void* d_out, int out_size, void* d_ws, size_t ws_size,
                              hipStream_t stream) {
    const float* l0 = (const float*)d_in[0];
    const float* r0 = (const float*)d_in[1];
    const float* l1 = (const float*)d_in[2];
    const float* r1 = (const float*)d_in[3];
    // d_in[4] is max_disp (=192) — hard-coded as DD = 64 above.
    float* out = (float*)d_out;

    // 2 s * 2 half * 32 c * 24 h-strips = 3072 blocks
    const unsigned nBlocks = 2u * 2u * CC * NHQ;
    hipLaunchKernelGGL(cost_volume_kernel, dim3(nBlocks), dim3(256), 0, stream,
                       l0, r0, l1, r1, out);
}

// Round 6
// 156.916 us; speedup vs baseline: 1.1127x; 1.1127x over previous
//
#include <hip/hip_runtime.h>

// Problem constants (fixed by setup_inputs: shape (1,32,96,240), max_disp=192)
#define CC   32          // channels per input
#define C2   64          // 2*CC
#define DD   64          // disparities = 192/3
#define HH   96
#define WW   240
#define W4   60          // WW/4 float4 chunks per row
#define F4_PER_SLICE (HH * W4)      // 5760 float4 per (s,c,d) slice = 92160 B
#define THREADS 320                  // 5 waves; 5760 / 320 = 18 float4/thread exactly

typedef float vf4 __attribute__((ext_vector_type(4)));

// Right half: out[h][w] = (w>=d) ? src[h][w-d] : 0.   With d = 4q + r, the
// shifted (unaligned) source window [4f-d .. 4f-d+3] is covered by two ALIGNED
// float4 loads A=src4[f-q-1], B=src4[f-q] and a static shuffle by r (block-
// uniform -> no divergence, compile-time shuffle). Components whose source
// index is out-of-row/negative are always masked to 0, so junk reads from the
// previous row's tail / clamped index 0 are harmless (verified at edges).
template<int R>
__device__ __forceinline__ void right_loop(const vf4* __restrict__ src4,
                                           vf4* __restrict__ o4,
                                           unsigned f, unsigned w4,
                                           int dd, int q) {
#pragma unroll
    for (int i = 0; i < 18; ++i) {
        const int a = (int)(w4 * 4u) - dd;       // mask: a + j >= 0
        int iB = (int)f - q; if (iB < 0) iB = 0;
        const vf4 B = src4[iB];
        vf4 v;
        if constexpr (R == 0) {
            v = B;
        } else {
            int iA = (int)f - q - 1; if (iA < 0) iA = 0;
            const vf4 A = src4[iA];
            if constexpr (R == 1)      v = __builtin_shufflevector(A, B, 3, 4, 5, 6);
            else if constexpr (R == 2) v = __builtin_shufflevector(A, B, 2, 3, 4, 5);
            else                       v = __builtin_shufflevector(A, B, 1, 2, 3, 4);
        }
        v.x = (a + 0 >= 0) ? v.x : 0.0f;
        v.y = (a + 1 >= 0) ? v.y : 0.0f;
        v.z = (a + 2 >= 0) ? v.z : 0.0f;
        v.w = (a + 3 >= 0) ? v.w : 0.0f;
        __builtin_nontemporal_store(v, &o4[f]);
        f += THREADS;
        w4 += 20u; if (w4 >= 60u) w4 -= 60u;
    }
}

__global__ __launch_bounds__(THREADS) void cost_volume_kernel(
        const float* __restrict__ l0, const float* __restrict__ r0,
        const float* __restrict__ l1, const float* __restrict__ r1,
        float* __restrict__ out) {
    const unsigned b = blockIdx.x;          // b == ((s*C2 + c)*DD + d)
    const unsigned d = b & 63u;
    const unsigned c = (b >> 6) & 63u;
    const unsigned s = b >> 12;

    const float* Lp = s ? l1 : l0;
    const float* Rp = s ? r1 : r0;
    const bool left = (c < CC);
    const float* src = left ? (Lp + c * (HH * WW))
                            : (Rp + (c - CC) * (HH * WW));
    const vf4* src4 = reinterpret_cast<const vf4*>(src);

    vf4* o4 = reinterpret_cast<vf4*>(out) + (size_t)b * F4_PER_SLICE;

    unsigned f  = threadIdx.x;              // float4 index within slice
    unsigned w4 = f % 60u;                  // float4 phase within row (+20 mod 60 per iter)
    const int dd = (int)d;

    if (left) {
#pragma unroll
        for (int i = 0; i < 18; ++i) {
            const int a = (int)(w4 * 4u) - dd;
            const vf4 x = src4[f];
            vf4 v;
            v.x = (a + 0 >= 0) ? x.x : 0.0f;
            v.y = (a + 1 >= 0) ? x.y : 0.0f;
            v.z = (a + 2 >= 0) ? x.z : 0.0f;
            v.w = (a + 3 >= 0) ? x.w : 0.0f;
            __builtin_nontemporal_store(v, &o4[f]);
            f += THREADS;
            w4 += 20u; if (w4 >= 60u) w4 -= 60u;
        }
    } else {
        const int q = dd >> 2;
        switch (dd & 3) {                    // block-uniform: scalar branch
            case 0: right_loop<0>(src4, o4, f, w4, dd, q); break;
            case 1: right_loop<1>(src4, o4, f, w4, dd, q); break;
            case 2: right_loop<2>(src4, o4, f, w4, dd, q); break;
            default: right_loop<3>(src4, o4, f, w4, dd, q); break;
        }
    }
}

extern "C" void kernel_launch(void* const* d_in, const int* in_sizes, int n_in,
                              void* d_out, int out_size, void* d_ws, size_t ws_size,
                              hipStream_t stream) {
    const float* l0 = (const float*)d_in[0];
    const float* r0 = (const float*)d_in[1];
    const float* l1 = (const float*)d_in[2];
    const float* r1 = (const float*)d_in[3];
    // d_in[4] is max_disp (=192) — hard-coded as DD = 64 above.
    float* out = (float*)d_out;

    // One block per (s,c,d) slice: 2*64*64 = 8192 blocks
    const unsigned nBlocks = 2u * C2 * DD;
    hipLaunchKernelGGL(cost_volume_kernel, dim3(nBlocks), dim3(THREADS), 0, stream,
                       l0, r0, l1, r1, out);
}